// Round 10
// baseline (411.957 us; speedup 1.0000x reference)
//
#include <hip/hip_runtime.h>
#include <hip/hip_bf16.h>
#include <hip/hip_cooperative_groups.h>

namespace cg = cooperative_groups;

// SparseToDense: scatter features [N,32] into dense [B=4, C=32, D=64, H=64, W=64].
// flat_idx (int32 on device) indexes B*D*H*W sites; output is NCDHW. DHW = 2^18.
//
// Strategy: invert the scatter via per-site chains -> no float atomics, output
// written densely, coalesced, exactly once (no zero-fill pass).
//   R6: nt LOADS regress -> cached loads. R7/R8: gather variants plateau;
//     controllable ~78 us (init+build+gather) vs ~126 us fixed harness fills.
//   R9: cooperative launch FAILED silently -- hardcoded 2048 blocks likely
//     exceeded this kernel's co-residency; error was never checked.
//   R10: occupancy-clamped cooperative grid + error check + in-call fallback
//     to the proven 3-kernel path (deterministic: same error every call).

#define DHW_LOG2 18
#define DHW (1 << DHW_LOG2)
#define C_CH 32
#define N_SITES_TOTAL (4 * DHW)   // B=4
#define COOP_THREADS 256
#define NUM_CU 256

typedef float floatx4 __attribute__((ext_vector_type(4)));

// ---------- fused cooperative kernel (grid-stride phases) ----------
__global__ __launch_bounds__(COOP_THREADS) void fused_kernel(
    const float* __restrict__ feats,
    const int* __restrict__ flat_idx,
    int* __restrict__ head,
    int* __restrict__ next,
    float* __restrict__ out,
    int n_active)
{
    cg::grid_group grid = cg::this_grid();
    const int t0 = blockIdx.x * blockDim.x + threadIdx.x;
    const int NT = gridDim.x * blockDim.x;

    // phase 1: init chain heads (4 MB)
    for (int i = t0; i < N_SITES_TOTAL; i += NT) head[i] = -1;
    grid.sync();

    // phase 2: build chains (400k device-scope atomicExch on L2-resident array)
    for (int i = t0; i < n_active; i += NT) {
        int s = flat_idx[i];
        next[i] = atomicExch(&head[s], i);
    }
    grid.sync();

    // phase 3: gather (pair variant: 2 threads/site, 16 channels each)
    for (int t = t0; t < 2 * N_SITES_TOTAL; t += NT) {
        int S = t >> 1;        // site
        int h = t & 1;         // channel half: h*16 .. h*16+15
        int b  = S >> DHW_LOG2;
        int sp = S & (DHW - 1);

        floatx4 a0 = (floatx4)0.f, a1 = (floatx4)0.f,
                a2 = (floatx4)0.f, a3 = (floatx4)0.f;

        int p = head[S];
        while (p >= 0) {
            const floatx4* row = (const floatx4*)(feats + ((size_t)p * C_CH + h * 16));
            int pn = next[p];                 // issue next-hop early
            floatx4 f0 = row[0];              // 64 B half-row: 1 fill + 3 L1 hits
            floatx4 f1 = row[1];
            floatx4 f2 = row[2];
            floatx4 f3 = row[3];
            a0 += f0; a1 += f1; a2 += f2; a3 += f3;
            p = pn;
        }

        float* o = out + (((size_t)(b * C_CH + h * 16)) << DHW_LOG2) + sp;
        float acc[16] = {
            a0.x, a0.y, a0.z, a0.w,  a1.x, a1.y, a1.z, a1.w,
            a2.x, a2.y, a2.z, a2.w,  a3.x, a3.y, a3.z, a3.w };
        #pragma unroll
        for (int j = 0; j < 16; ++j)
            __builtin_nontemporal_store(acc[j], o + ((size_t)j << DHW_LOG2));
    }
}

// ---------- R7 fallback path (proven 203.8 us) ----------
__global__ __launch_bounds__(256) void init_head_kernel(int* __restrict__ head, int n)
{
    int t = blockIdx.x * blockDim.x + threadIdx.x;
    if (t < n) head[t] = -1;
}

__global__ __launch_bounds__(256) void build_chains_kernel(
    const int* __restrict__ flat_idx,
    int* __restrict__ head,
    int* __restrict__ next,
    int n_active)
{
    int i = blockIdx.x * blockDim.x + threadIdx.x;
    if (i >= n_active) return;
    int s = flat_idx[i];
    next[i] = atomicExch(&head[s], i);
}

__global__ __launch_bounds__(256) void gather_kernel(
    const float* __restrict__ feats,
    const int* __restrict__ head,
    const int* __restrict__ next,
    float* __restrict__ out)
{
    int t = blockIdx.x * blockDim.x + threadIdx.x;
    int S = t >> 1;
    int h = t & 1;
    int b  = S >> DHW_LOG2;
    int sp = S & (DHW - 1);

    floatx4 a0 = (floatx4)0.f, a1 = (floatx4)0.f, a2 = (floatx4)0.f, a3 = (floatx4)0.f;

    int p = head[S];
    while (p >= 0) {
        const floatx4* row = (const floatx4*)(feats + ((size_t)p * C_CH + h * 16));
        int pn = next[p];
        floatx4 f0 = row[0];
        floatx4 f1 = row[1];
        floatx4 f2 = row[2];
        floatx4 f3 = row[3];
        a0 += f0; a1 += f1; a2 += f2; a3 += f3;
        p = pn;
    }

    float* o = out + (((size_t)(b * C_CH + h * 16)) << DHW_LOG2) + sp;
    float acc[16] = {
        a0.x, a0.y, a0.z, a0.w,  a1.x, a1.y, a1.z, a1.w,
        a2.x, a2.y, a2.z, a2.w,  a3.x, a3.y, a3.z, a3.w };
    #pragma unroll
    for (int j = 0; j < 16; ++j)
        __builtin_nontemporal_store(acc[j], o + ((size_t)j << DHW_LOG2));
}

// ---------- minimal fallback if workspace too small (never expected) ----------
__global__ __launch_bounds__(256) void zero_kernel(float4* __restrict__ out, int n4)
{
    int t = blockIdx.x * blockDim.x + threadIdx.x;
    if (t < n4) out[t] = make_float4(0.f, 0.f, 0.f, 0.f);
}

__global__ __launch_bounds__(256) void scatter_atomic_kernel(
    const float* __restrict__ feats,
    const int* __restrict__ flat_idx,
    float* __restrict__ out,
    int n_active)
{
    int t = blockIdx.x * blockDim.x + threadIdx.x;
    int i = t >> 5, c = t & 31;
    if (i >= n_active) return;
    int s = flat_idx[i];
    atomicAdd(&out[(((size_t)(s >> DHW_LOG2) * C_CH + c) << DHW_LOG2) + (s & (DHW - 1))],
              feats[(size_t)i * C_CH + c]);
}

extern "C" void kernel_launch(void* const* d_in, const int* in_sizes, int n_in,
                              void* d_out, int out_size, void* d_ws, size_t ws_size,
                              hipStream_t stream) {
    const float* feats = (const float*)d_in[0];
    const int*   idx   = (const int*)d_in[1];
    float*       out   = (float*)d_out;
    int n_active = in_sizes[1];   // 400000

    size_t head_bytes = (size_t)N_SITES_TOTAL * sizeof(int);      // 4 MB
    size_t next_bytes = (size_t)n_active * sizeof(int);           // 1.6 MB

    if (ws_size < head_bytes + next_bytes) {
        int n4 = out_size >> 2;
        zero_kernel<<<(n4 + 255) / 256, 256, 0, stream>>>((float4*)out, n4);
        int total = n_active * C_CH;
        scatter_atomic_kernel<<<(total + 255) / 256, 256, 0, stream>>>(feats, idx, out, n_active);
        return;
    }

    int* head = (int*)d_ws;
    int* next = (int*)((char*)d_ws + head_bytes);

    // Occupancy-clamped cooperative grid (R9 failed with hardcoded 2048).
    int blocksPerCU = 0;
    hipError_t oerr = hipOccupancyMaxActiveBlocksPerMultiprocessor(
        &blocksPerCU, fused_kernel, COOP_THREADS, 0);

    hipError_t lerr = hipErrorUnknown;
    if (oerr == hipSuccess && blocksPerCU > 0) {
        int coop_blocks = blocksPerCU * NUM_CU;
        int max_useful = (2 * N_SITES_TOTAL + COOP_THREADS - 1) / COOP_THREADS;
        if (coop_blocks > max_useful) coop_blocks = max_useful;

        void* args[] = { (void*)&feats, (void*)&idx, (void*)&head,
                         (void*)&next, (void*)&out, (void*)&n_active };
        lerr = hipLaunchCooperativeKernel((void*)fused_kernel,
                                          dim3(coop_blocks), dim3(COOP_THREADS),
                                          args, 0, stream);
    }

    if (lerr != hipSuccess) {
        // Deterministic fallback (same error every call -> capture-consistent):
        // proven R7 3-kernel path.
        init_head_kernel<<<(N_SITES_TOTAL + 255) / 256, 256, 0, stream>>>(head, N_SITES_TOTAL);
        build_chains_kernel<<<(n_active + 255) / 256, 256, 0, stream>>>(idx, head, next, n_active);
        gather_kernel<<<(2 * N_SITES_TOTAL) / 256, 256, 0, stream>>>(feats, head, next, out);
    }
}